// Round 6
// baseline (231.477 us; speedup 1.0000x reference)
//
#include <hip/hip_runtime.h>
#include <hip/hip_bf16.h>

#define T_TOK 16384
#define D_DIM 1024
#define E_EXP 8

// 256x256 tile, BK=32, 4-slot LDS ring, 8 waves (2M x 4N)
#define BM2 256
#define BN2 256
#define BK2 32
#define NT2 (D_DIM / BK2)          // 32 K-tiles
#define SLOT_ELE (BM2 * BK2)       // 8192 bf16 = 16 KB per matrix per slot

#define CNT_STRIDE 64    // pad expert counters to 256B apart

typedef __attribute__((ext_vector_type(4))) float f32x4;
typedef __attribute__((ext_vector_type(8))) short bf16x8;
typedef __attribute__((ext_vector_type(4))) unsigned short u16x4;

static __device__ __forceinline__ unsigned short f2bf(float f) {
    unsigned int u = __float_as_uint(f);
    unsigned int r = 0x7FFFu + ((u >> 16) & 1u);
    return (unsigned short)((u + r) >> 16);
}

// direct-to-LDS 16B async copy: global src per-lane, LDS dest = uniform base + lane*16
#define GLOAD_LDS16(gp, lp) \
    __builtin_amdgcn_global_load_lds( \
        (const __attribute__((address_space(1))) void*)(gp), \
        (__attribute__((address_space(3))) void*)(lp), 16, 0, 0)

// ---------------- expert_w fp32 -> bf16 ----------------
__global__ __launch_bounds__(256) void convert_w_kernel(
    const float* __restrict__ w, unsigned short* __restrict__ o) {
    const int n4 = (E_EXP * D_DIM * D_DIM) / 4;
    for (int i = blockIdx.x * 256 + threadIdx.x; i < n4; i += gridDim.x * 256) {
        f32x4 v = ((const f32x4*)w)[i];
        u16x4 p;
        p[0] = f2bf(v[0]); p[1] = f2bf(v[1]); p[2] = f2bf(v[2]); p[3] = f2bf(v[3]);
        ((u16x4*)o)[i] = p;
    }
}

// ---------------- router: 64 tokens/block + fused x->bf16 ----------------
#define TPB_TOK 64
__global__ __launch_bounds__(256) void router_kernel(
    const float* __restrict__ x, const float* __restrict__ gate_w,
    const float* __restrict__ gate_b, float* __restrict__ out_logits,
    float* __restrict__ out_sel, int* __restrict__ counts,
    int* __restrict__ pair_token, float* __restrict__ pair_weight,
    unsigned short* __restrict__ xbf) {
    __shared__ float gw[E_EXP][D_DIM];          // 32 KB
    __shared__ float gb_s[E_EXP];
    __shared__ float logits_s[TPB_TOK][E_EXP];  // 2 KB
    __shared__ int   cnt_local[E_EXP];
    __shared__ int   gbase[E_EXP];
    __shared__ int   ent_e[TPB_TOK][2];
    __shared__ int   ent_pos[TPB_TOK][2];
    __shared__ float ent_w[TPB_TOK][2];

    const int tid = threadIdx.x;
    for (int i = tid; i < E_EXP * D_DIM; i += 256) gw[0][i] = gate_w[i];
    if (tid < E_EXP) { gb_s[tid] = gate_b[tid]; cnt_local[tid] = 0; }
    __syncthreads();

    const int lane = tid & 63, wv = tid >> 6;
    const int tl = lane >> 2, g = lane & 3;     // 4 lanes per token
    const int jt = wv * 16 + tl;                // token within block [0,64)
    const int t = blockIdx.x * TPB_TOK + jt;

    float acc[E_EXP] = {};
    const f32x4* xr = (const f32x4*)(x + (size_t)t * D_DIM);
    u16x4* xw = (u16x4*)(xbf + (size_t)t * D_DIM);
    for (int i = g; i < D_DIM / 4; i += 4) {
        f32x4 xv = xr[i];
        u16x4 pk;
        pk[0] = f2bf(xv[0]); pk[1] = f2bf(xv[1]); pk[2] = f2bf(xv[2]); pk[3] = f2bf(xv[3]);
        xw[i] = pk;                              // fused fp32->bf16 copy of x
        #pragma unroll
        for (int e = 0; e < E_EXP; ++e) {
            f32x4 gv = ((const f32x4*)(&gw[e][0]))[i];
            acc[e] += xv[0] * gv[0] + xv[1] * gv[1] + xv[2] * gv[2] + xv[3] * gv[3];
        }
    }
    #pragma unroll
    for (int e = 0; e < E_EXP; ++e) {
        float v = acc[e];
        v += __shfl_xor(v, 1, 64);
        v += __shfl_xor(v, 2, 64);
        acc[e] = v;
    }
    if (g == 0) {
        float l[E_EXP], p[E_EXP];
        float m = -1e30f;
        #pragma unroll
        for (int e = 0; e < E_EXP; ++e) { l[e] = acc[e] + gb_s[e]; m = fmaxf(m, l[e]); }
        float s = 0.f;
        #pragma unroll
        for (int e = 0; e < E_EXP; ++e) { p[e] = expf(l[e] - m); s += p[e]; }
        #pragma unroll
        for (int e = 0; e < E_EXP; ++e) p[e] /= s;
        // top-2 on probs, strict > => lowest index wins ties (matches jax.lax.top_k)
        int e0 = 0; float p0 = p[0];
        #pragma unroll
        for (int e = 1; e < E_EXP; ++e) if (p[e] > p0) { p0 = p[e]; e0 = e; }
        int e1 = -1; float p1 = -1e30f;
        #pragma unroll
        for (int e = 0; e < E_EXP; ++e) if (e != e0 && p[e] > p1) { p1 = p[e]; e1 = e; }
        float denom = p0 + p1;
        float w0 = p0 / denom, w1 = p1 / denom;
        #pragma unroll
        for (int e = 0; e < E_EXP; ++e) logits_s[jt][e] = l[e];
        out_sel[t * 2 + 0] = (float)e0;
        out_sel[t * 2 + 1] = (float)e1;
        int p0i = atomicAdd(&cnt_local[e0], 1);   // LDS atomic: cheap
        int p1i = atomicAdd(&cnt_local[e1], 1);
        ent_e[jt][0] = e0; ent_pos[jt][0] = p0i; ent_w[jt][0] = w0;
        ent_e[jt][1] = e1; ent_pos[jt][1] = p1i; ent_w[jt][1] = w1;
    }
    __syncthreads();
    if (tid < E_EXP) gbase[tid] = atomicAdd(&counts[tid * CNT_STRIDE], cnt_local[tid]);
    if (tid < TPB_TOK * E_EXP / 4) {
        f32x4 v = ((const f32x4*)&logits_s[0][0])[tid];
        ((f32x4*)(out_logits + (size_t)blockIdx.x * TPB_TOK * E_EXP))[tid] = v;
    }
    __syncthreads();
    if (g == 0) {
        #pragma unroll
        for (int k = 0; k < 2; ++k) {
            int e = ent_e[jt][k];
            int pos = gbase[e] + ent_pos[jt][k];
            pair_token[e * T_TOK + pos] = t;
            pair_weight[e * T_TOK + pos] = ent_w[jt][k];
        }
    }
}

// ---------------- grouped gather-GEMM, 256^2 tile, fine-phase ring pipeline ----------
// 4-slot LDS ring (slot = kt & 3), BK=32. Per K-tile: 2 phases x {8 ds_read_b128,
// 2 global_load_lds (tile kt+2), barrier, 16 MFMA in setprio(1), barrier}.
// vmcnt(6) once per K-tile: per-wave 4 loads/tile; tile kt+1 (4) + A(kt+2) (2)
// may stay in flight while tile kt's 4 drain. Ring-4 => slot being written
// (kt+2) was last read at tile kt-2: >=4 barriers ago. No swizzle: 64B rows
// hit all 32 banks evenly for this read pattern.
__global__ __launch_bounds__(512, 2) void moe_gemm_kernel(
    const unsigned short* __restrict__ xbf, const unsigned short* __restrict__ wbf,
    const float* __restrict__ expert_b, const int* __restrict__ counts,
    const int* __restrict__ pair_token, const float* __restrict__ pair_weight,
    float* __restrict__ out) {
    const int flat = blockIdx.x;
    const int cls = flat & 7;          // XCD class: 4 n-tiles of one (e,mt) share it
    const int nt  = (flat >> 3) & 3;   // n-tile
    const int sup = flat >> 5;
    const int group = sup * 8 + cls;   // (expert, m-tile), bijective over [0,512)
    const int e = group >> 6;
    const int m_base = (group & 63) * BM2;
    const int cnt = counts[e * CNT_STRIDE];
    if (m_base >= cnt) return;
    const int n_base = nt * BN2;

    __shared__ unsigned short Asl[4 * SLOT_ELE];   // 64 KB
    __shared__ unsigned short Bsl[4 * SLOT_ELE];   // 64 KB
    __shared__ int tok_s[BM2];
    __shared__ float w_s[BM2];

    const int tid = threadIdx.x;
    if (tid < BM2) {
        int m = m_base + tid;
        int mc = (m < cnt) ? m : (cnt - 1);  // clamp: garbage rows skipped in epilogue
        tok_s[tid] = pair_token[e * T_TOK + mc];
        w_s[tid]   = pair_weight[e * T_TOK + mc];
    }
    __syncthreads();

    const int lane = tid & 63;
    const int wid = tid >> 6;
    const int wm = wid >> 2, wn = wid & 3;   // 2x4 waves, each 128(m) x 64(n)
    const int lr = lane & 15, lk = lane >> 4;

    // staging: gload g covers rows g*128 + (tid>>2); 4 lanes x 16B per 64B row
    const int srcrow = tid >> 2;
    const int scol = (tid & 3) * 8;
    const unsigned short* wb = wbf + ((size_t)e << 20);
    const unsigned short* agp0 = xbf + (size_t)tok_s[srcrow] * D_DIM + scol;
    const unsigned short* agp1 = xbf + (size_t)tok_s[128 + srcrow] * D_DIM + scol;
    const unsigned short* bgp0 = wb + (size_t)(n_base + srcrow) * D_DIM + scol;
    const unsigned short* bgp1 = wb + (size_t)(n_base + 128 + srcrow) * D_DIM + scol;
    const int lds0 = (wid * 16) * BK2;         // wave-uniform LDS elem offsets
    const int lds1 = (128 + wid * 16) * BK2;

    f32x4 acc[8][4] = {};

#define STG_A(slot, kt) do { \
        GLOAD_LDS16(agp0 + (kt) * BK2, &Asl[(slot) * SLOT_ELE + lds0]); \
        GLOAD_LDS16(agp1 + (kt) * BK2, &Asl[(slot) * SLOT_ELE + lds1]); } while (0)
#define STG_B(slot, kt) do { \
        GLOAD_LDS16(bgp0 + (kt) * BK2, &Bsl[(slot) * SLOT_ELE + lds0]); \
        GLOAD_LDS16(bgp1 + (kt) * BK2, &Bsl[(slot) * SLOT_ELE + lds1]); } while (0)

#define TILE(kt, u) do { \
        const unsigned short* Ab = &Asl[(u) * SLOT_ELE]; \
        const unsigned short* Bb = &Bsl[(u) * SLOT_ELE]; \
        bf16x8 a[4], b[4]; \
        /* phase A: stage A(kt+2), residency wait, quadrant m0-3 */ \
        if ((kt) < NT2 - 2) { \
            STG_A(((kt) + 2) & 3, (kt) + 2); \
            asm volatile("s_waitcnt vmcnt(6)" ::: "memory"); \
        } else if ((kt) == NT2 - 2) { \
            asm volatile("s_waitcnt vmcnt(4)" ::: "memory"); \
        } else { \
            asm volatile("s_waitcnt vmcnt(0)" ::: "memory"); \
        } \
        __builtin_amdgcn_s_barrier(); \
        _Pragma("unroll") \
        for (int nf = 0; nf < 4; ++nf) \
            b[nf] = *(const bf16x8*)&Bb[(wn * 64 + nf * 16 + lr) * BK2 + lk * 8]; \
        _Pragma("unroll") \
        for (int mf = 0; mf < 4; ++mf) \
            a[mf] = *(const bf16x8*)&Ab[(wm * 128 + mf * 16 + lr) * BK2 + lk * 8]; \
        __builtin_amdgcn_s_setprio(1); \
        _Pragma("unroll") \
        for (int mf = 0; mf < 4; ++mf) \
            _Pragma("unroll") \
            for (int nf = 0; nf < 4; ++nf) \
                acc[mf][nf] = __builtin_amdgcn_mfma_f32_16x16x32_bf16(a[mf], b[nf], acc[mf][nf], 0, 0, 0); \
        __builtin_amdgcn_s_setprio(0); \
        __builtin_amdgcn_s_barrier(); \
        /* phase B: early a-reads, stage B(kt+2), quadrant m4-7 (b reused) */ \
        _Pragma("unroll") \
        for (int mf = 0; mf < 4; ++mf) \
            a[mf] = *(const bf16x8*)&Ab[(wm * 128 + (4 + mf) * 16 + lr) * BK2 + lk * 8]; \
        if ((kt) < NT2 - 2) STG_B(((kt) + 2) & 3, (kt) + 2); \
        __builtin_amdgcn_s_barrier(); \
        __builtin_amdgcn_s_setprio(1); \
        _Pragma("unroll") \
        for (int mf = 0; mf < 4; ++mf) \
            _Pragma("unroll") \
            for (int nf = 0; nf < 4; ++nf) \
                acc[4 + mf][nf] = __builtin_amdgcn_mfma_f32_16x16x32_bf16(a[mf], b[nf], acc[4 + mf][nf], 0, 0, 0); \
        __builtin_amdgcn_s_setprio(0); \
        __builtin_amdgcn_s_barrier(); \
    } while (0)

    // prologue: tiles 0 and 1 fully staged (8 loads/wave in flight)
    STG_A(0, 0); STG_B(0, 0);
    STG_A(1, 1); STG_B(1, 1);

    for (int kt4 = 0; kt4 < NT2; kt4 += 4) {   // slot static per sub-tile
        TILE(kt4 + 0, 0);
        TILE(kt4 + 1, 1);
        TILE(kt4 + 2, 2);
        TILE(kt4 + 3, 3);
    }
#undef TILE
#undef STG_A
#undef STG_B

    // epilogue: out[t, gn] += w * (acc + bias)
    float bias[4];
    #pragma unroll
    for (int nf = 0; nf < 4; ++nf)
        bias[nf] = expert_b[e * D_DIM + n_base + wn * 64 + nf * 16 + lr];
    #pragma unroll
    for (int mf = 0; mf < 8; ++mf) {
        #pragma unroll
        for (int j = 0; j < 4; ++j) {
            int mi = wm * 128 + mf * 16 + lk * 4 + j;
            if (m_base + mi >= cnt) continue;
            int tk = tok_s[mi];
            float wgt = w_s[mi];
            size_t obase = (size_t)tk * D_DIM + n_base + wn * 64 + lr;
            #pragma unroll
            for (int nf = 0; nf < 4; ++nf)
                atomicAdd(out + obase + nf * 16, (acc[mf][nf][j] + bias[nf]) * wgt);
        }
    }
}

extern "C" void kernel_launch(void* const* d_in, const int* in_sizes, int n_in,
                              void* d_out, int out_size, void* d_ws, size_t ws_size,
                              hipStream_t stream) {
    const float* x        = (const float*)d_in[0];
    const float* gate_w   = (const float*)d_in[1];
    const float* gate_b   = (const float*)d_in[2];
    const float* expert_w = (const float*)d_in[3];
    const float* expert_b = (const float*)d_in[4];

    float* out        = (float*)d_out;                      // [T, D]
    float* out_logits = out + (size_t)T_TOK * D_DIM;        // [T, E]
    float* out_sel    = out_logits + (size_t)T_TOK * E_EXP; // [T, 2] as float

    char* ws = (char*)d_ws;
    unsigned short* wbf = (unsigned short*)ws;                         // 16 MB
    unsigned short* xbf = (unsigned short*)(ws + 16777216);            // 32 MB
    int*   counts      = (int*)(ws + 50331648);                        // 2 KB (+pad)
    int*   pair_token  = (int*)(ws + 50331648 + 4096);                 // 512 KB
    float* pair_weight = (float*)(ws + 50331648 + 4096 + 524288);      // 512 KB

    hipMemsetAsync(counts, 0, E_EXP * CNT_STRIDE * sizeof(int), stream);
    hipMemsetAsync(out, 0, (size_t)T_TOK * D_DIM * sizeof(float), stream);

    convert_w_kernel<<<2048, 256, 0, stream>>>(expert_w, wbf);
    router_kernel<<<T_TOK / TPB_TOK, 256, 0, stream>>>(x, gate_w, gate_b, out_logits,
                                                       out_sel, counts, pair_token,
                                                       pair_weight, xbf);
    // 8 XCD-classes x 4 n-tiles x 64 m-tile-groups = 2048 blocks (inactive exit early)
    moe_gemm_kernel<<<2048, 512, 0, stream>>>(xbf, wbf, expert_b, counts,
                                              pair_token, pair_weight, out);
}

// Round 7
// 148.096 us; speedup vs baseline: 1.5630x; 1.5630x over previous
//
#include <hip/hip_runtime.h>
#include <hip/hip_bf16.h>

#define T_TOK 16384
#define D_DIM 1024
#define E_EXP 8
#define NPAIR 28

#define BM 128
#define BN 128
#define BK 64            // 128 B/row in bf16
#define NT_K (D_DIM / BK)

#define CNT_STRIDE 64    // pad pair counters to 256B apart

typedef __attribute__((ext_vector_type(4))) float f32x4;
typedef __attribute__((ext_vector_type(2))) float f32x2;
typedef __attribute__((ext_vector_type(8))) short bf16x8;
typedef __attribute__((ext_vector_type(4))) unsigned short u16x4;

static __device__ __forceinline__ unsigned short f2bf(float f) {
    unsigned int u = __float_as_uint(f);
    unsigned int r = 0x7FFFu + ((u >> 16) & 1u);
    return (unsigned short)((u + r) >> 16);
}

// direct-to-LDS 16B async copy: global src per-lane, LDS dest = uniform base + lane*16
#define GLOAD_LDS16(gp, lp) \
    __builtin_amdgcn_global_load_lds( \
        (const __attribute__((address_space(1))) void*)(gp), \
        (__attribute__((address_space(3))) void*)(lp), 16, 0, 0)

// ---------------- expert_w fp32 -> bf16 ----------------
__global__ __launch_bounds__(256) void convert_w_kernel(
    const float* __restrict__ w, unsigned short* __restrict__ o) {
    const int n4 = (E_EXP * D_DIM * D_DIM) / 4;
    for (int i = blockIdx.x * 256 + threadIdx.x; i < n4; i += gridDim.x * 256) {
        f32x4 v = ((const f32x4*)w)[i];
        u16x4 p;
        p[0] = f2bf(v[0]); p[1] = f2bf(v[1]); p[2] = f2bf(v[2]); p[3] = f2bf(v[3]);
        ((u16x4*)o)[i] = p;
    }
}

// ---------------- router: 64 tokens/block, pair-grouped scatter + fused x->bf16 ------
#define TPB_TOK 64
__global__ __launch_bounds__(256) void router_kernel(
    const float* __restrict__ x, const float* __restrict__ gate_w,
    const float* __restrict__ gate_b, float* __restrict__ out_logits,
    float* __restrict__ out_sel, int* __restrict__ counts,
    int* __restrict__ pair_token, f32x2* __restrict__ pair_w,
    unsigned short* __restrict__ xbf) {
    __shared__ float gw[E_EXP][D_DIM];          // 32 KB
    __shared__ float gb_s[E_EXP];
    __shared__ float logits_s[TPB_TOK][E_EXP];  // 2 KB
    __shared__ int   cnt_local[NPAIR];
    __shared__ int   gbase[NPAIR];
    __shared__ int   ent_p[TPB_TOK];
    __shared__ int   ent_pos[TPB_TOK];
    __shared__ f32x2 ent_w[TPB_TOK];

    const int tid = threadIdx.x;
    for (int i = tid; i < E_EXP * D_DIM; i += 256) gw[0][i] = gate_w[i];
    if (tid < E_EXP) gb_s[tid] = gate_b[tid];
    if (tid < NPAIR) cnt_local[tid] = 0;
    __syncthreads();

    const int lane = tid & 63, wv = tid >> 6;
    const int tl = lane >> 2, g = lane & 3;     // 4 lanes per token
    const int jt = wv * 16 + tl;                // token within block [0,64)
    const int t = blockIdx.x * TPB_TOK + jt;

    float acc[E_EXP] = {};
    const f32x4* xr = (const f32x4*)(x + (size_t)t * D_DIM);
    u16x4* xw = (u16x4*)(xbf + (size_t)t * D_DIM);
    for (int i = g; i < D_DIM / 4; i += 4) {
        f32x4 xv = xr[i];
        u16x4 pk;
        pk[0] = f2bf(xv[0]); pk[1] = f2bf(xv[1]); pk[2] = f2bf(xv[2]); pk[3] = f2bf(xv[3]);
        xw[i] = pk;                              // fused fp32->bf16 copy of x
        #pragma unroll
        for (int e = 0; e < E_EXP; ++e) {
            f32x4 gv = ((const f32x4*)(&gw[e][0]))[i];
            acc[e] += xv[0] * gv[0] + xv[1] * gv[1] + xv[2] * gv[2] + xv[3] * gv[3];
        }
    }
    #pragma unroll
    for (int e = 0; e < E_EXP; ++e) {
        float v = acc[e];
        v += __shfl_xor(v, 1, 64);
        v += __shfl_xor(v, 2, 64);
        acc[e] = v;
    }
    if (g == 0) {
        float l[E_EXP], p[E_EXP];
        float m = -1e30f;
        #pragma unroll
        for (int e = 0; e < E_EXP; ++e) { l[e] = acc[e] + gb_s[e]; m = fmaxf(m, l[e]); }
        float s = 0.f;
        #pragma unroll
        for (int e = 0; e < E_EXP; ++e) { p[e] = expf(l[e] - m); s += p[e]; }
        #pragma unroll
        for (int e = 0; e < E_EXP; ++e) p[e] /= s;
        // top-2 on probs, strict > => lowest index wins ties (matches jax.lax.top_k)
        int e0 = 0; float p0 = p[0];
        #pragma unroll
        for (int e = 1; e < E_EXP; ++e) if (p[e] > p0) { p0 = p[e]; e0 = e; }
        int e1 = -1; float p1 = -1e30f;
        #pragma unroll
        for (int e = 0; e < E_EXP; ++e) if (e != e0 && p[e] > p1) { p1 = p[e]; e1 = e; }
        float denom = p0 + p1;
        float w0 = p0 / denom, w1 = p1 / denom;
        #pragma unroll
        for (int e = 0; e < E_EXP; ++e) logits_s[jt][e] = l[e];
        out_sel[t * 2 + 0] = (float)e0;
        out_sel[t * 2 + 1] = (float)e1;
        // unordered pair (lo,hi), weights follow the experts
        int lo = min(e0, e1), hi = max(e0, e1);
        float wl = (e0 < e1) ? w0 : w1;
        float wh = (e0 < e1) ? w1 : w0;
        int pp = (lo * (15 - lo)) / 2 + (hi - lo - 1);   // triangular index [0,28)
        int pos = atomicAdd(&cnt_local[pp], 1);          // LDS atomic: cheap
        ent_p[jt] = pp; ent_pos[jt] = pos;
        f32x2 wv2; wv2[0] = wl; wv2[1] = wh;
        ent_w[jt] = wv2;
    }
    __syncthreads();
    if (tid < NPAIR) gbase[tid] = atomicAdd(&counts[tid * CNT_STRIDE], cnt_local[tid]);
    if (tid < TPB_TOK * E_EXP / 4) {
        f32x4 v = ((const f32x4*)&logits_s[0][0])[tid];
        ((f32x4*)(out_logits + (size_t)blockIdx.x * TPB_TOK * E_EXP))[tid] = v;
    }
    __syncthreads();
    if (g == 0) {
        int pp = ent_p[jt];
        int pos = gbase[pp] + ent_pos[jt];
        pair_token[pp * T_TOK + pos] = t;
        pair_w[pp * T_TOK + pos] = ent_w[jt];
    }
}

// ---------------- schedule: compact tile list over 28 pair groups ----------------
__global__ void schedule_kernel(const int* __restrict__ counts,
                                int* __restrict__ tiles, int* __restrict__ ntiles) {
    if (threadIdx.x != 0 || blockIdx.x != 0) return;
    int idx = 0, p = 0;
    for (int lo = 0; lo < E_EXP - 1; ++lo)
        for (int hi = lo + 1; hi < E_EXP; ++hi, ++p) {
            int c = counts[p * CNT_STRIDE];
            for (int m = 0; m < c; m += BM)
                tiles[idx++] = p | (lo << 5) | (hi << 8) | (m << 12);
        }
    *ntiles = idx;
}

// ---------------- pair-grouped GEMM: out[t] = wl*(Wlo x+blo) + wh*(Whi x+bhi) --------
// Single-buffer m97 structure; A + B_lo + B_hi staged per K-step (48 KB LDS);
// both-sides XOR swizzle (128B rows, chunk^(row&7)); NO atomics: one plain
// coalesced store per output element. XCD-chunked: 8 n-tiles of one tile get
// flat ids congruent mod 8 -> same XCD L2 -> A-tile reuse.
__global__ __launch_bounds__(256, 2) void moe_gemm_kernel(
    const unsigned short* __restrict__ xbf, const unsigned short* __restrict__ wbf,
    const float* __restrict__ expert_b, const int* __restrict__ counts,
    const int* __restrict__ ntiles, const int* __restrict__ tiles,
    const int* __restrict__ pair_token, const f32x2* __restrict__ pair_w,
    float* __restrict__ out) {
    const int flat = blockIdx.x;
    const int cls = flat & 7;          // XCD class
    const int nt  = (flat >> 3) & 7;   // n-tile
    const int sup = flat >> 6;
    const int gidx = sup * 8 + cls;    // tile-list index
    if (gidx >= *ntiles) return;
    const int entry = tiles[gidx];
    const int p = entry & 31;
    const int lo = (entry >> 5) & 7, hi = (entry >> 8) & 7;
    const int m_base = entry >> 12;
    const int cnt = counts[p * CNT_STRIDE];
    const int n_base = nt * BN;

    __shared__ unsigned short As[BM * BK];    // 16 KB each, linear (swizzled content)
    __shared__ unsigned short B0s[BM * BK];
    __shared__ unsigned short B1s[BM * BK];
    __shared__ int tok_s[BM];
    __shared__ f32x2 w_s[BM];

    const int tid = threadIdx.x;
    if (tid < BM) {
        int m = m_base + tid;
        int mc = (m < cnt) ? m : (cnt - 1);  // clamp: garbage rows skipped in epilogue
        tok_s[tid] = pair_token[p * T_TOK + mc];
        w_s[tid]   = pair_w[p * T_TOK + mc];
    }
    __syncthreads();

    const int lane = tid & 63;
    const int w = tid >> 6;
    const int lr = lane & 15, lk = lane >> 4;
    const int wr = w >> 1, wc = w & 1;       // 2x2 waves, 64x64 each

    // staging geometry: wave w, issue i covers rows [i*32+w*8, +8), 128 B each
    const int srow = lane >> 3;                       // row within 8-row group
    const int scol = 8 * ((lane & 7) ^ srow);         // swizzled source column (elems)
    const unsigned short* wb0 = wbf + ((size_t)lo << 20);
    const unsigned short* wb1 = wbf + ((size_t)hi << 20);
    const unsigned short* agp[4];
    const unsigned short* b0gp[4];
    const unsigned short* b1gp[4];
    int loff[4];
    #pragma unroll
    for (int i = 0; i < 4; ++i) {
        int R = i * 32 + w * 8 + srow;
        agp[i]  = xbf + (size_t)tok_s[R] * D_DIM + scol;
        b0gp[i] = wb0 + (size_t)(n_base + R) * D_DIM + scol;
        b1gp[i] = wb1 + (size_t)(n_base + R) * D_DIM + scol;
        loff[i] = (i * 32 + w * 8) * BK;              // wave-uniform LDS elem offset
    }

    f32x4 acc0[4][4] = {};
    f32x4 acc1[4][4] = {};

    for (int k0 = 0; k0 < D_DIM; k0 += BK) {
        #pragma unroll
        for (int i = 0; i < 4; ++i) {
            GLOAD_LDS16(agp[i] + k0, &As[loff[i]]);
            GLOAD_LDS16(b0gp[i] + k0, &B0s[loff[i]]);
            GLOAD_LDS16(b1gp[i] + k0, &B1s[loff[i]]);
        }
        __syncthreads();   // drains vmcnt(0): tile resident
        #pragma unroll
        for (int kk = 0; kk < 2; ++kk) {
            bf16x8 a[4], b[4], c[4];
            #pragma unroll
            for (int m = 0; m < 4; ++m) {
                int R = wr * 64 + m * 16 + lr;
                int cb = (kk * 64 + lk * 16) ^ ((R & 7) << 4);
                a[m] = *(const bf16x8*)((const char*)As + R * 128 + cb);
            }
            #pragma unroll
            for (int n = 0; n < 4; ++n) {
                int R = wc * 64 + n * 16 + lr;
                int cb = (kk * 64 + lk * 16) ^ ((R & 7) << 4);
                b[n] = *(const bf16x8*)((const char*)B0s + R * 128 + cb);
            }
            #pragma unroll
            for (int m = 0; m < 4; ++m)
                #pragma unroll
                for (int n = 0; n < 4; ++n)
                    acc0[m][n] = __builtin_amdgcn_mfma_f32_16x16x32_bf16(a[m], b[n], acc0[m][n], 0, 0, 0);
            #pragma unroll
            for (int n = 0; n < 4; ++n) {
                int R = wc * 64 + n * 16 + lr;
                int cb = (kk * 64 + lk * 16) ^ ((R & 7) << 4);
                c[n] = *(const bf16x8*)((const char*)B1s + R * 128 + cb);
            }
            #pragma unroll
            for (int m = 0; m < 4; ++m)
                #pragma unroll
                for (int n = 0; n < 4; ++n)
                    acc1[m][n] = __builtin_amdgcn_mfma_f32_16x16x32_bf16(a[m], c[n], acc1[m][n], 0, 0, 0);
        }
        __syncthreads();
    }

    // epilogue: out[t, gn] = wl*(acc0+blo) + wh*(acc1+bhi)   (plain stores, no atomics)
    float blo[4], bhi[4];
    #pragma unroll
    for (int n = 0; n < 4; ++n) {
        int gn = n_base + wc * 64 + n * 16 + lr;
        blo[n] = expert_b[lo * D_DIM + gn];
        bhi[n] = expert_b[hi * D_DIM + gn];
    }
    #pragma unroll
    for (int m = 0; m < 4; ++m) {
        #pragma unroll
        for (int j = 0; j < 4; ++j) {
            int mi = wr * 64 + m * 16 + lk * 4 + j;
            if (m_base + mi >= cnt) continue;
            int tk = tok_s[mi];
            f32x2 wgt = w_s[mi];
            size_t obase = (size_t)tk * D_DIM + n_base + wc * 64 + lr;
            #pragma unroll
            for (int n = 0; n < 4; ++n)
                out[obase + n * 16] = wgt[0] * (acc0[m][n][j] + blo[n])
                                    + wgt[1] * (acc1[m][n][j] + bhi[n]);
        }
    }
}

extern "C" void kernel_launch(void* const* d_in, const int* in_sizes, int n_in,
                              void* d_out, int out_size, void* d_ws, size_t ws_size,
                              hipStream_t stream) {
    const float* x        = (const float*)d_in[0];
    const float* gate_w   = (const float*)d_in[1];
    const float* gate_b   = (const float*)d_in[2];
    const float* expert_w = (const float*)d_in[3];
    const float* expert_b = (const float*)d_in[4];

    float* out        = (float*)d_out;                      // [T, D]
    float* out_logits = out + (size_t)T_TOK * D_DIM;        // [T, E]
    float* out_sel    = out_logits + (size_t)T_TOK * E_EXP; // [T, 2] as float

    char* ws = (char*)d_ws;
    unsigned short* wbf = (unsigned short*)ws;                         // 16 MB
    unsigned short* xbf = (unsigned short*)(ws + 16777216);            // 32 MB
    size_t off = 50331648;
    int*   counts     = (int*)(ws + off);                              // 28*64 ints = 7 KB
    int*   ntiles     = (int*)(ws + off + 8192);
    int*   tiles      = (int*)(ws + off + 8192 + 256);                 // <=155 entries
    int*   pair_token = (int*)(ws + off + 16384);                      // 28*T*4 = 1.75 MB
    f32x2* pair_w     = (f32x2*)(ws + off + 16384 + 1835008);          // 28*T*8 = 3.5 MB

    hipMemsetAsync(counts, 0, NPAIR * CNT_STRIDE * sizeof(int), stream);

    convert_w_kernel<<<2048, 256, 0, stream>>>(expert_w, wbf);
    router_kernel<<<T_TOK / TPB_TOK, 256, 0, stream>>>(x, gate_w, gate_b, out_logits,
                                                       out_sel, counts, pair_token,
                                                       pair_w, xbf);
    schedule_kernel<<<1, 64, 0, stream>>>(counts, tiles, ntiles);
    // sup(20) x nt(8) x cls(8): covers up to 160 tiles (max possible = 155)
    moe_gemm_kernel<<<20 * 64, 256, 0, stream>>>(xbf, wbf, expert_b, counts,
                                                 ntiles, tiles, pair_token, pair_w, out);
}